// Round 1
// 290.960 us; speedup vs baseline: 1.1027x; 1.1027x over previous
//
#include <hip/hip_runtime.h>
#include <hip/hip_fp16.h>

// out[M,N] = fp16( a[M,K] @ (w_q[K,N] * scale[K/G,N]) ), G=128, all dims 4096.
// Harness dtype contract: fp16 tensors passed/returned as FLOAT32.
// Round 1 change: replace the m97-structure 128^2 GEMM (790 TF, barrier-drain
// bound) with a 256^2 / BK=64 / 512-thread counted-vmcnt pipeline (T3+T4+T5):
// ring of 4 k-half LDS slots per operand, stage distance 3 phases, vmcnt(8)
// in steady state (never 0), one raw s_barrier per phase, setprio around the
// 32-MFMA cluster. Prep pass split into prep_a/prep_w (bodies unchanged) for
// rocprof attribution.
#define MDIM 4096
#define NDIM 4096
#define KDIM 4096
#define NT 256

typedef _Float16 f16x8 __attribute__((ext_vector_type(8)));
typedef float f32x4 __attribute__((ext_vector_type(4)));
typedef unsigned int u32;
typedef unsigned short u16;

__device__ inline __half2 as_half2(u32 u) { return __builtin_bit_cast(__half2, u); }
__device__ inline u32 as_u32(__half2 h) { return __builtin_bit_cast(u32, h); }
// __builtin_amdgcn_cvt_pkrtz returns __fp16 ext_vector(2); bit-cast directly.
__device__ inline u32 pkrtz(float a, float b) {
  return __builtin_bit_cast(u32, __builtin_amdgcn_cvt_pkrtz(a, b));
}

// async global -> LDS, 16 B/lane. LDS dst must be wave-uniform base + lane*16.
__device__ inline void load16_to_lds(const void* g, void* l) {
  __builtin_amdgcn_global_load_lds(
      (__attribute__((address_space(1))) const u32*)g,
      (__attribute__((address_space(3))) u32*)l,
      16, 0, 0);
}

template <int VM>
__device__ __forceinline__ void wait_vmcnt() {
  if constexpr (VM == 8)
    asm volatile("s_waitcnt vmcnt(8)" ::: "memory");
  else if constexpr (VM == 4)
    asm volatile("s_waitcnt vmcnt(4)" ::: "memory");
  else
    asm volatile("s_waitcnt vmcnt(0)" ::: "memory");
}

// ---- prep_a: A fp32 -> fp16 copy (exact: values are fp16-representable) ----
__global__ __launch_bounds__(NT) void prep_a(const float* __restrict__ A,
                                             _Float16* __restrict__ A16) {
  const size_t base = ((size_t)blockIdx.x * NT + threadIdx.x) * 8;
  const float4 f0 = *(const float4*)(A + base);
  const float4 f1 = *(const float4*)(A + base + 4);
  u32 pk[4];
  pk[0] = pkrtz(f0.x, f0.y);
  pk[1] = pkrtz(f0.z, f0.w);
  pk[2] = pkrtz(f1.x, f1.y);
  pk[3] = pkrtz(f1.z, f1.w);
  *(uint4*)(A16 + base) = *(const uint4*)pk;
}

// ---- prep_w: dequant Wq [K][N] + transpose -> Wt f16 [N][K], 64x64 tiles ----
#define TSTR 68  // u16 stride for transpose staging
__global__ __launch_bounds__(NT) void prep_w(const int* __restrict__ Wq,
                                             const float* __restrict__ Sc,
                                             _Float16* __restrict__ Wt) {
  __shared__ __align__(16) u16 Ls[64 * TSTR];
  const int tid = threadIdx.x;
  const int n0 = (blockIdx.x & 63) * 64;
  const int k0 = (blockIdx.x >> 6) * 64;
  const int g = k0 >> 7;  // 64-tile lies within one 128-group

  // phase 1: coalesced read + dequant, LDS [k][n]
#pragma unroll
  for (int r = 0; r < 4; ++r) {
    const int c = r * 256 + tid;
    const int krow = c >> 4;
    const int col4 = (c & 15) * 4;
    const int4 v = *(const int4*)(Wq + (size_t)(k0 + krow) * NDIM + n0 + col4);
    const float4 s = *(const float4*)(Sc + (size_t)g * NDIM + n0 + col4);
    // fp16 bits of (1024+v): 0x6400|v; hfma gives single-rounded v*s.
    __half2 s01 = __floats2half2_rn(s.x, s.y);
    __half2 s23 = __floats2half2_rn(s.z, s.w);
    const __half2 kneg = __half2half2(__float2half(-1024.0f));
    __half2 nb01 = __hmul2(s01, kneg), nb23 = __hmul2(s23, kneg);
    u32 u01 = (u32)v.x | ((u32)v.y << 16) | 0x64006400u;
    u32 u23 = (u32)v.z | ((u32)v.w << 16) | 0x64006400u;
    u32 pk[2];
    pk[0] = as_u32(__hfma2(as_half2(u01), s01, nb01));
    pk[1] = as_u32(__hfma2(as_half2(u23), s23, nb23));
    *(uint2*)&Ls[(size_t)krow * TSTR + col4] = *(const uint2*)pk;
  }
  __syncthreads();

  // phase 2: transposed read from LDS, coalesced 16B writes to Wt [n][k]
#pragma unroll
  for (int r = 0; r < 2; ++r) {
    const int idx = r * 256 + tid;
    const int n = idx >> 3;
    const int kc = (idx & 7) * 8;
    u16 tmp[8];
#pragma unroll
    for (int j = 0; j < 8; ++j) tmp[j] = Ls[(size_t)(kc + j) * TSTR + n];
    *(uint4*)(Wt + (size_t)(n0 + n) * KDIM + k0 + kc) = *(const uint4*)tmp;
  }
}

// ---------------- 256x256 counted-vmcnt pipelined f16 GEMM ----------------
// LDS: ring of 4 slots per operand, each slot = one k-half piece
//   [256 rows][4 phys chunks of 16B] (16 KB). Phase p uses slot p&3 and
//   stages the piece for phase p+3 into slot (p+3)&3 (last read at p-1,
//   whose reads completed before any wave could pass p's entry barrier).
// Swizzle: physical chunk = logical ^ ((row>>1)&3). Applied to the per-lane
// GLOBAL source (LDS dst stays linear for global_load_lds), and to the
// ds_read_b128 fragment address -> balanced 8 dwords/bank, no conflicts.
__global__ __launch_bounds__(512, 2) void gemm_f16(const _Float16* __restrict__ A16,
                                                   const _Float16* __restrict__ Wt,
                                                   float* __restrict__ C) {
  __shared__ __align__(16) _Float16 As[4 * 256 * 32];  // 64 KB
  __shared__ __align__(16) _Float16 Bs[4 * 256 * 32];  // 64 KB

  const int tid = threadIdx.x;
  const int bx = blockIdx.x & 15;  // n-block
  const int by = blockIdx.x >> 4;  // m-block
  const int m_base = by * 256;
  const int n_base = bx * 256;

  const int wave = tid >> 6;
  const int lane = tid & 63;
  const int l15 = lane & 15;
  const int quad = lane >> 4;
  const int mq = wave >> 2;  // 0..1 : 128-row band
  const int nq = wave & 3;   // 0..3 : 64-col band
  const int gq = (l15 >> 1) & 3;       // row-swizzle term (row ≡ l15 mod 16)
  const int pchunk = quad ^ gq;        // physical 16B chunk for frag reads

  f32x4 acc[8][4];
#pragma unroll
  for (int i = 0; i < 8; ++i)
#pragma unroll
    for (int j = 0; j < 4; ++j) acc[i][j] = (f32x4)0.0f;

  // stage pieces (A khalf + B khalf) for phase p into slot p&3.
  // 2+2 global_load_lds per thread = 4 vmcnt events per wave per stage.
  auto stage = [&](int p) {
    const int T = p >> 1;        // K-tile
    const int h = p & 1;         // k-half within tile
    const int s = p & 3;         // slot
    const size_t kof = (size_t)T * 64 + (size_t)h * 32;
#pragma unroll
    for (int L = 0; L < 2; ++L) {
      const int cc = L * 512 + tid;        // 0..1023 : (row, phys chunk)
      const int row = cc >> 2;
      const int lch = (cc & 3) ^ ((row >> 1) & 3);  // logical chunk at phys cc&3
      load16_to_lds(A16 + (size_t)(m_base + row) * KDIM + kof + lch * 8,
                    (char*)As + (size_t)s * 16384 + (size_t)cc * 16);
    }
#pragma unroll
    for (int L = 0; L < 2; ++L) {
      const int cc = L * 512 + tid;
      const int row = cc >> 2;
      const int lch = (cc & 3) ^ ((row >> 1) & 3);
      load16_to_lds(Wt + (size_t)(n_base + row) * KDIM + kof + lch * 8,
                    (char*)Bs + (size_t)s * 16384 + (size_t)cc * 16);
    }
  };

  auto phase_body = [&](int p, bool dostage) {
    __builtin_amdgcn_s_barrier();
    asm volatile("" ::: "memory");  // no LDS access hoists above the barrier
    const int s = p & 3;
    const _Float16* Ab = (const _Float16*)((const char*)As + (size_t)s * 16384);
    const _Float16* Bb = (const _Float16*)((const char*)Bs + (size_t)s * 16384);
    f16x8 af[8], bf[4];
#pragma unroll
    for (int i = 0; i < 8; ++i) {
      const int row = mq * 128 + i * 16 + l15;
      af[i] = *(const f16x8*)(Ab + (size_t)row * 32 + pchunk * 8);
    }
#pragma unroll
    for (int j = 0; j < 4; ++j) {
      const int row = nq * 64 + j * 16 + l15;
      bf[j] = *(const f16x8*)(Bb + (size_t)row * 32 + pchunk * 8);
    }
    if (dostage) stage(p + 3);
    asm volatile("s_waitcnt lgkmcnt(0)" ::: "memory");
    __builtin_amdgcn_sched_barrier(0);  // keep MFMAs below the wait (rule 18)
    __builtin_amdgcn_s_setprio(1);
#pragma unroll
    for (int i = 0; i < 8; ++i)
#pragma unroll
      for (int j = 0; j < 4; ++j)
        acc[i][j] = __builtin_amdgcn_mfma_f32_16x16x32_f16(af[i], bf[j],
                                                           acc[i][j], 0, 0, 0);
    __builtin_amdgcn_s_setprio(0);
  };

  // prologue: pieces for phases 0,1,2 (12 vmcnt events in flight)
  stage(0);
  stage(1);
  stage(2);

  // 128 phases = 64 K-tiles x 2 k-halves. vmcnt(8): phases p-1,p-2 in
  // flight, phase p's pieces (staged at p-3) guaranteed landed before the
  // entry barrier (all waves execute the wait pre-barrier).
  for (int p = 0; p < 125; ++p) {
    wait_vmcnt<8>();
    phase_body(p, true);
  }
  wait_vmcnt<8>();
  phase_body(125, false);
  wait_vmcnt<4>();
  phase_body(126, false);
  wait_vmcnt<0>();
  phase_body(127, false);

  // epilogue: C/D layout col=lane&15, row=quad*4+reg; fp16-round, store f32
#pragma unroll
  for (int i = 0; i < 8; ++i) {
#pragma unroll
    for (int j = 0; j < 4; ++j) {
      const int col = n_base + nq * 64 + j * 16 + l15;
#pragma unroll
      for (int r = 0; r < 4; ++r) {
        const int row = m_base + mq * 128 + i * 16 + quad * 4 + r;
        C[(size_t)row * NDIM + col] = __half2float(__float2half(acc[i][j][r]));
      }
    }
  }
}

// ---------------- fallback: fused single-kernel (round-3, 331 us) --------
#define STR 72
__global__ __launch_bounds__(NT) void qgemm_fused(
    const float* __restrict__ A, const int* __restrict__ Wq,
    const float* __restrict__ Sc, float* __restrict__ C) {
  __shared__ __align__(16) _Float16 As[128 * STR];
  __shared__ __align__(16) _Float16 Bs[128 * STR];
  const int tid = threadIdx.x;
  const int bx = blockIdx.x & 31, by = blockIdx.x >> 5;
  const int m_base = by * 128, n_base = bx * 128;
  const int wave = tid >> 6, lane = tid & 63;
  const int l15 = lane & 15, quad = lane >> 4;
  const int wm = (wave & 1) * 64, wn = (wave >> 1) * 64;
  const int bn_local = tid & 127, bk_half = (tid >> 7) * 8;
  const int gn = n_base + bn_local;
  f32x4 acc[4][4];
#pragma unroll
  for (int i = 0; i < 4; ++i)
#pragma unroll
    for (int j = 0; j < 4; ++j) acc[i][j] = (f32x4)0.0f;
  for (int kt = 0; kt < KDIM / 64; ++kt) {
    const int k0 = kt * 64;
    __syncthreads();
#pragma unroll
    for (int i = 0; i < 8; ++i) {
      const int c = i * 256 + tid;
      const int row = c >> 4, col4 = (c & 15) * 4;
      const float4 f = *(const float4*)(A + (size_t)(m_base + row) * KDIM + k0 + col4);
      u32 pk[2];
      pk[0] = pkrtz(f.x, f.y);
      pk[1] = pkrtz(f.z, f.w);
      *(uint2*)&As[(size_t)row * STR + col4] = *(const uint2*)pk;
    }
    {
      const __half hs = __float2half(Sc[(size_t)(k0 >> 7) * NDIM + gn]);
      const __half2 s2 = __half2half2(hs);
      const __half2 nb2 = __half2half2(__hmul(hs, __float2half(-1024.0f)));
#pragma unroll
      for (int it = 0; it < 4; ++it) {
        const int k = bk_half + it * 16;
        u32 v[8];
#pragma unroll
        for (int j = 0; j < 8; ++j)
          v[j] = (u32)Wq[(size_t)(k0 + k + j) * NDIM + gn];
        u32 pk[4];
#pragma unroll
        for (int p = 0; p < 4; ++p) {
          u32 u = v[2 * p] | (v[2 * p + 1] << 16) | 0x64006400u;
          pk[p] = as_u32(__hfma2(as_half2(u), s2, nb2));
        }
        *(uint4*)&Bs[(size_t)bn_local * STR + k] = *(const uint4*)pk;
      }
    }
    __syncthreads();
#pragma unroll
    for (int ks = 0; ks < 64; ks += 32) {
      f16x8 af[4], bf[4];
#pragma unroll
      for (int i = 0; i < 4; ++i)
        af[i] = *(const f16x8*)&As[(size_t)(wm + i * 16 + l15) * STR + ks + quad * 8];
#pragma unroll
      for (int j = 0; j < 4; ++j)
        bf[j] = *(const f16x8*)&Bs[(size_t)(wn + j * 16 + l15) * STR + ks + quad * 8];
#pragma unroll
      for (int i = 0; i < 4; ++i)
#pragma unroll
        for (int j = 0; j < 4; ++j)
          acc[i][j] = __builtin_amdgcn_mfma_f32_16x16x32_f16(af[i], bf[j],
                                                             acc[i][j], 0, 0, 0);
    }
  }
#pragma unroll
  for (int i = 0; i < 4; ++i)
#pragma unroll
    for (int j = 0; j < 4; ++j) {
      const int col = n_base + wn + j * 16 + l15;
#pragma unroll
      for (int r = 0; r < 4; ++r) {
        const int row = m_base + wm + i * 16 + quad * 4 + r;
        C[(size_t)row * NDIM + col] = __half2float(__float2half(acc[i][j][r]));
      }
    }
}

extern "C" void kernel_launch(void* const* d_in, const int* in_sizes, int n_in,
                              void* d_out, int out_size, void* d_ws, size_t ws_size,
                              hipStream_t stream) {
  const float* a = (const float*)d_in[0];
  const int* wq = (const int*)d_in[1];
  const float* sc = (const float*)d_in[2];
  float* out = (float*)d_out;

  const size_t a16_bytes = (size_t)MDIM * KDIM * 2;  // 32 MiB
  const size_t wt_bytes = (size_t)NDIM * KDIM * 2;   // 32 MiB

  if (ws_size >= a16_bytes + wt_bytes) {
    _Float16* a16 = (_Float16*)d_ws;
    _Float16* wt = (_Float16*)((char*)d_ws + a16_bytes);
    prep_a<<<(MDIM * KDIM) / (NT * 8), NT, 0, stream>>>(a, a16);
    prep_w<<<(KDIM / 64) * (NDIM / 64), NT, 0, stream>>>(wq, sc, wt);
    gemm_f16<<<(MDIM / 256) * (NDIM / 256), 512, 0, stream>>>(a16, wt, out);
  } else {
    qgemm_fused<<<(MDIM / 128) * (NDIM / 128), NT, 0, stream>>>(a, wq, sc, out);
  }
}

// Round 2
// 286.040 us; speedup vs baseline: 1.1217x; 1.0172x over previous
//
#include <hip/hip_runtime.h>
#include <hip/hip_fp16.h>

// out[M,N] = fp16( a[M,K] @ (w_q[K,N] * scale[K/G,N]) ), G=128, all dims 4096.
// Harness dtype contract: fp16 tensors passed/returned as FLOAT32.
// Round 2 change: prep pass rewritten (gemm_f16 byte-identical to round 1).
//  - k-pair packed dequant: one u32 = (v[2kp]*s, v[2kp+1]*s) via the 0x6400
//    hfma2 trick -> transpose staging in u32 LDS [n][33] (odd dword stride).
//    Write bank=(n+kp)%32 and read bank=(n+k2c+j)%32 are both 2-way = free
//    (old u16 path was 16-way on reads). 8 b32 writes + 8 b32 reads/thread.
//  - prep_a/prep_w re-merged into ONE dispatch (W tiles + A copy blocks run
//    concurrently; removes one kernel-boundary serialization).
#define MDIM 4096
#define NDIM 4096
#define KDIM 4096
#define NT 256
#define WBLK 4096

typedef _Float16 f16x8 __attribute__((ext_vector_type(8)));
typedef float f32x4 __attribute__((ext_vector_type(4)));
typedef unsigned int u32;
typedef unsigned short u16;

__device__ inline __half2 as_half2(u32 u) { return __builtin_bit_cast(__half2, u); }
__device__ inline u32 as_u32(__half2 h) { return __builtin_bit_cast(u32, h); }
// __builtin_amdgcn_cvt_pkrtz returns __fp16 ext_vector(2); bit-cast directly.
__device__ inline u32 pkrtz(float a, float b) {
  return __builtin_bit_cast(u32, __builtin_amdgcn_cvt_pkrtz(a, b));
}

// async global -> LDS, 16 B/lane. LDS dst must be wave-uniform base + lane*16.
__device__ inline void load16_to_lds(const void* g, void* l) {
  __builtin_amdgcn_global_load_lds(
      (__attribute__((address_space(1))) const u32*)g,
      (__attribute__((address_space(3))) u32*)l,
      16, 0, 0);
}

template <int VM>
__device__ __forceinline__ void wait_vmcnt() {
  if constexpr (VM == 8)
    asm volatile("s_waitcnt vmcnt(8)" ::: "memory");
  else if constexpr (VM == 4)
    asm volatile("s_waitcnt vmcnt(4)" ::: "memory");
  else
    asm volatile("s_waitcnt vmcnt(0)" ::: "memory");
}

// ---- fused prepass: blocks [0,4096) dequant+transpose W, rest copy A ----
__global__ __launch_bounds__(NT) void prep(const float* __restrict__ A,
                                           _Float16* __restrict__ A16,
                                           const int* __restrict__ Wq,
                                           const float* __restrict__ Sc,
                                           _Float16* __restrict__ Wt) {
  // u32 staging [n][k-pair], stride 33 dwords: write bank (n+kp)%32 (2-way),
  // read bank (n+k2c+j)%32 (2-way). 8.25 KB -> high occupancy.
  __shared__ u32 Lt[64 * 33];
  const int tid = threadIdx.x;

  if (blockIdx.x >= WBLK) {
    // ---- A fp32 -> fp16 (exact: values are fp16-representable) ----
    const size_t b = blockIdx.x - WBLK;
    const size_t base = (b * NT + tid) * 8;
    const float4 f0 = *(const float4*)(A + base);
    const float4 f1 = *(const float4*)(A + base + 4);
    u32 pk[4];
    pk[0] = pkrtz(f0.x, f0.y);
    pk[1] = pkrtz(f0.z, f0.w);
    pk[2] = pkrtz(f1.x, f1.y);
    pk[3] = pkrtz(f1.z, f1.w);
    *(uint4*)(A16 + base) = *(const uint4*)pk;
    return;
  }

  // ---- W: dequant Wq [K][N] + transpose -> Wt f16 [N][K], 64x64 tile ----
  const int n0 = (blockIdx.x & 63) * 64;
  const int k0 = (blockIdx.x >> 6) * 64;
  const int g = k0 >> 7;  // 64-tile lies within one 128-group

  // phase 1: coalesced read of two adjacent k-rows, dequant to packed k-pair
#pragma unroll
  for (int r = 0; r < 2; ++r) {
    const int idx = r * 256 + tid;
    const int kp = idx >> 4;          // k-pair index 0..31
    const int col4 = (idx & 15) * 4;  // n within tile, 4 at a time
    const int4 va = *(const int4*)(Wq + (size_t)(k0 + 2 * kp) * NDIM + n0 + col4);
    const int4 vb = *(const int4*)(Wq + (size_t)(k0 + 2 * kp + 1) * NDIM + n0 + col4);
    const float4 s = *(const float4*)(Sc + (size_t)g * NDIM + n0 + col4);
    const float sf[4] = {s.x, s.y, s.z, s.w};
    const int av[4] = {va.x, va.y, va.z, va.w};
    const int bv[4] = {vb.x, vb.y, vb.z, vb.w};
#pragma unroll
    for (int i = 0; i < 4; ++i) {
      // fp16 bits of (1024+v): 0x6400|v; hfma gives single-rounded v*s.
      const __half hs = __float2half(sf[i]);
      const __half2 s2 = __half2half2(hs);
      const __half2 nb = __half2half2(__hmul(hs, __float2half(-1024.0f)));
      const u32 u = (u32)av[i] | ((u32)bv[i] << 16) | 0x64006400u;
      // u32 holds (w[2kp]*s, w[2kp+1]*s) = the contiguous k-pair for Wt[n].
      Lt[(size_t)(col4 + i) * 33 + kp] = as_u32(__hfma2(as_half2(u), s2, nb));
    }
  }
  __syncthreads();

  // phase 2: gather 4 k-pair dwords per thread, coalesced 16B writes to Wt
#pragma unroll
  for (int r = 0; r < 2; ++r) {
    const int idx = r * 256 + tid;
    const int n = idx >> 3;          // 0..63
    const int k2c = (idx & 7) * 4;   // dword column 0..28 (= k/2)
    u32 v[4];
#pragma unroll
    for (int j = 0; j < 4; ++j) v[j] = Lt[(size_t)n * 33 + k2c + j];
    *(uint4*)(Wt + (size_t)(n0 + n) * KDIM + k0 + k2c * 2) = *(const uint4*)v;
  }
}

// ---------------- 256x256 counted-vmcnt pipelined f16 GEMM ----------------
// LDS: ring of 4 slots per operand, each slot = one k-half piece
//   [256 rows][4 phys chunks of 16B] (16 KB). Phase p uses slot p&3 and
//   stages the piece for phase p+3 into slot (p+3)&3 (last read at p-1,
//   whose reads completed before any wave could pass p's entry barrier).
// Swizzle: physical chunk = logical ^ ((row>>1)&3). Applied to the per-lane
// GLOBAL source (LDS dst stays linear for global_load_lds), and to the
// ds_read_b128 fragment address -> balanced 8 dwords/bank, no conflicts.
__global__ __launch_bounds__(512, 2) void gemm_f16(const _Float16* __restrict__ A16,
                                                   const _Float16* __restrict__ Wt,
                                                   float* __restrict__ C) {
  __shared__ __align__(16) _Float16 As[4 * 256 * 32];  // 64 KB
  __shared__ __align__(16) _Float16 Bs[4 * 256 * 32];  // 64 KB

  const int tid = threadIdx.x;
  const int bx = blockIdx.x & 15;  // n-block
  const int by = blockIdx.x >> 4;  // m-block
  const int m_base = by * 256;
  const int n_base = bx * 256;

  const int wave = tid >> 6;
  const int lane = tid & 63;
  const int l15 = lane & 15;
  const int quad = lane >> 4;
  const int mq = wave >> 2;  // 0..1 : 128-row band
  const int nq = wave & 3;   // 0..3 : 64-col band
  const int gq = (l15 >> 1) & 3;       // row-swizzle term (row ≡ l15 mod 16)
  const int pchunk = quad ^ gq;        // physical 16B chunk for frag reads

  f32x4 acc[8][4];
#pragma unroll
  for (int i = 0; i < 8; ++i)
#pragma unroll
    for (int j = 0; j < 4; ++j) acc[i][j] = (f32x4)0.0f;

  // stage pieces (A khalf + B khalf) for phase p into slot p&3.
  // 2+2 global_load_lds per thread = 4 vmcnt events per wave per stage.
  auto stage = [&](int p) {
    const int T = p >> 1;        // K-tile
    const int h = p & 1;         // k-half within tile
    const int s = p & 3;         // slot
    const size_t kof = (size_t)T * 64 + (size_t)h * 32;
#pragma unroll
    for (int L = 0; L < 2; ++L) {
      const int cc = L * 512 + tid;        // 0..1023 : (row, phys chunk)
      const int row = cc >> 2;
      const int lch = (cc & 3) ^ ((row >> 1) & 3);  // logical chunk at phys cc&3
      load16_to_lds(A16 + (size_t)(m_base + row) * KDIM + kof + lch * 8,
                    (char*)As + (size_t)s * 16384 + (size_t)cc * 16);
    }
#pragma unroll
    for (int L = 0; L < 2; ++L) {
      const int cc = L * 512 + tid;
      const int row = cc >> 2;
      const int lch = (cc & 3) ^ ((row >> 1) & 3);
      load16_to_lds(Wt + (size_t)(n_base + row) * KDIM + kof + lch * 8,
                    (char*)Bs + (size_t)s * 16384 + (size_t)cc * 16);
    }
  };

  auto phase_body = [&](int p, bool dostage) {
    __builtin_amdgcn_s_barrier();
    asm volatile("" ::: "memory");  // no LDS access hoists above the barrier
    const int s = p & 3;
    const _Float16* Ab = (const _Float16*)((const char*)As + (size_t)s * 16384);
    const _Float16* Bb = (const _Float16*)((const char*)Bs + (size_t)s * 16384);
    f16x8 af[8], bf[4];
#pragma unroll
    for (int i = 0; i < 8; ++i) {
      const int row = mq * 128 + i * 16 + l15;
      af[i] = *(const f16x8*)(Ab + (size_t)row * 32 + pchunk * 8);
    }
#pragma unroll
    for (int j = 0; j < 4; ++j) {
      const int row = nq * 64 + j * 16 + l15;
      bf[j] = *(const f16x8*)(Bb + (size_t)row * 32 + pchunk * 8);
    }
    if (dostage) stage(p + 3);
    asm volatile("s_waitcnt lgkmcnt(0)" ::: "memory");
    __builtin_amdgcn_sched_barrier(0);  // keep MFMAs below the wait (rule 18)
    __builtin_amdgcn_s_setprio(1);
#pragma unroll
    for (int i = 0; i < 8; ++i)
#pragma unroll
      for (int j = 0; j < 4; ++j)
        acc[i][j] = __builtin_amdgcn_mfma_f32_16x16x32_f16(af[i], bf[j],
                                                           acc[i][j], 0, 0, 0);
    __builtin_amdgcn_s_setprio(0);
  };

  // prologue: pieces for phases 0,1,2 (12 vmcnt events in flight)
  stage(0);
  stage(1);
  stage(2);

  // 128 phases = 64 K-tiles x 2 k-halves. vmcnt(8): phases p-1,p-2 in
  // flight, phase p's pieces (staged at p-3) guaranteed landed before the
  // entry barrier (all waves execute the wait pre-barrier).
  for (int p = 0; p < 125; ++p) {
    wait_vmcnt<8>();
    phase_body(p, true);
  }
  wait_vmcnt<8>();
  phase_body(125, false);
  wait_vmcnt<4>();
  phase_body(126, false);
  wait_vmcnt<0>();
  phase_body(127, false);

  // epilogue: C/D layout col=lane&15, row=quad*4+reg; fp16-round, store f32
#pragma unroll
  for (int i = 0; i < 8; ++i) {
#pragma unroll
    for (int j = 0; j < 4; ++j) {
      const int col = n_base + nq * 64 + j * 16 + l15;
#pragma unroll
      for (int r = 0; r < 4; ++r) {
        const int row = m_base + mq * 128 + i * 16 + quad * 4 + r;
        C[(size_t)row * NDIM + col] = __half2float(__float2half(acc[i][j][r]));
      }
    }
  }
}

// ---------------- fallback: fused single-kernel (round-3, 331 us) --------
#define STR 72
__global__ __launch_bounds__(NT) void qgemm_fused(
    const float* __restrict__ A, const int* __restrict__ Wq,
    const float* __restrict__ Sc, float* __restrict__ C) {
  __shared__ __align__(16) _Float16 As[128 * STR];
  __shared__ __align__(16) _Float16 Bs[128 * STR];
  const int tid = threadIdx.x;
  const int bx = blockIdx.x & 31, by = blockIdx.x >> 5;
  const int m_base = by * 128, n_base = bx * 128;
  const int wave = tid >> 6, lane = tid & 63;
  const int l15 = lane & 15, quad = lane >> 4;
  const int wm = (wave & 1) * 64, wn = (wave >> 1) * 64;
  const int bn_local = tid & 127, bk_half = (tid >> 7) * 8;
  const int gn = n_base + bn_local;
  f32x4 acc[4][4];
#pragma unroll
  for (int i = 0; i < 4; ++i)
#pragma unroll
    for (int j = 0; j < 4; ++j) acc[i][j] = (f32x4)0.0f;
  for (int kt = 0; kt < KDIM / 64; ++kt) {
    const int k0 = kt * 64;
    __syncthreads();
#pragma unroll
    for (int i = 0; i < 8; ++i) {
      const int c = i * 256 + tid;
      const int row = c >> 4, col4 = (c & 15) * 4;
      const float4 f = *(const float4*)(A + (size_t)(m_base + row) * KDIM + k0 + col4);
      u32 pk[2];
      pk[0] = pkrtz(f.x, f.y);
      pk[1] = pkrtz(f.z, f.w);
      *(uint2*)&As[(size_t)row * STR + col4] = *(const uint2*)pk;
    }
    {
      const __half hs = __float2half(Sc[(size_t)(k0 >> 7) * NDIM + gn]);
      const __half2 s2 = __half2half2(hs);
      const __half2 nb2 = __half2half2(__hmul(hs, __float2half(-1024.0f)));
#pragma unroll
      for (int it = 0; it < 4; ++it) {
        const int k = bk_half + it * 16;
        u32 v[8];
#pragma unroll
        for (int j = 0; j < 8; ++j)
          v[j] = (u32)Wq[(size_t)(k0 + k + j) * NDIM + gn];
        u32 pk[4];
#pragma unroll
        for (int p = 0; p < 4; ++p) {
          u32 u = v[2 * p] | (v[2 * p + 1] << 16) | 0x64006400u;
          pk[p] = as_u32(__hfma2(as_half2(u), s2, nb2));
        }
        *(uint4*)&Bs[(size_t)bn_local * STR + k] = *(const uint4*)pk;
      }
    }
    __syncthreads();
#pragma unroll
    for (int ks = 0; ks < 64; ks += 32) {
      f16x8 af[4], bf[4];
#pragma unroll
      for (int i = 0; i < 4; ++i)
        af[i] = *(const f16x8*)&As[(size_t)(wm + i * 16 + l15) * STR + ks + quad * 8];
#pragma unroll
      for (int j = 0; j < 4; ++j)
        bf[j] = *(const f16x8*)&Bs[(size_t)(wn + j * 16 + l15) * STR + ks + quad * 8];
#pragma unroll
      for (int i = 0; i < 4; ++i)
#pragma unroll
        for (int j = 0; j < 4; ++j)
          acc[i][j] = __builtin_amdgcn_mfma_f32_16x16x32_f16(af[i], bf[j],
                                                             acc[i][j], 0, 0, 0);
    }
  }
#pragma unroll
  for (int i = 0; i < 4; ++i)
#pragma unroll
    for (int j = 0; j < 4; ++j) {
      const int col = n_base + wn + j * 16 + l15;
#pragma unroll
      for (int r = 0; r < 4; ++r) {
        const int row = m_base + wm + i * 16 + quad * 4 + r;
        C[(size_t)row * NDIM + col] = __half2float(__float2half(acc[i][j][r]));
      }
    }
}

extern "C" void kernel_launch(void* const* d_in, const int* in_sizes, int n_in,
                              void* d_out, int out_size, void* d_ws, size_t ws_size,
                              hipStream_t stream) {
  const float* a = (const float*)d_in[0];
  const int* wq = (const int*)d_in[1];
  const float* sc = (const float*)d_in[2];
  float* out = (float*)d_out;

  const size_t a16_bytes = (size_t)MDIM * KDIM * 2;  // 32 MiB
  const size_t wt_bytes = (size_t)NDIM * KDIM * 2;   // 32 MiB

  if (ws_size >= a16_bytes + wt_bytes) {
    _Float16* a16 = (_Float16*)d_ws;
    _Float16* wt = (_Float16*)((char*)d_ws + a16_bytes);
    const int a_blocks = (MDIM * KDIM) / (NT * 8);  // 8192
    prep<<<WBLK + a_blocks, NT, 0, stream>>>(a, a16, wq, sc, wt);
    gemm_f16<<<(MDIM / 256) * (NDIM / 256), 512, 0, stream>>>(a16, wt, out);
  } else {
    qgemm_fused<<<(MDIM / 128) * (NDIM / 128), NT, 0, stream>>>(a, wq, sc, out);
  }
}